// Round 11
// baseline (31.547 us; speedup 1.0000x reference)
//
#include <hip/hip_runtime.h>

#define Wd 512
#define Hd 512
#define NIMG 48                      // 16 batch * 3 channels
#define RB 8                         // output rows per tile (no halo staged)
#define NBLK (NIMG * (Hd / RB))      // 48*64 = 3072 blocks, one tile each
constexpr float INV_N = 1.0f / (float)((long long)NIMG * Hd * Wd);

// async global->LDS, 16 B per lane: HW writes lds_base + lane*16.
__device__ __forceinline__ void gload_lds16(const float* g, float* l) {
    __builtin_amdgcn_global_load_lds(
        (const __attribute__((address_space(1))) void*)g,
        (__attribute__((address_space(3))) void*)l, 16, 0, 0);
}

// Scharr on a 3x10 window; pixel j (0..7) uses cols j..j+2 of rows r0,r1,r2.
__device__ __forceinline__ float scharr_pix(const float r0[10], const float r1[10],
                                            const float r2[10], int j) {
    float tl = r0[j], tm = r0[j + 1], tr = r0[j + 2];
    float ml = r1[j],                  mr = r1[j + 2];
    float bl = r2[j], bm = r2[j + 1], br = r2[j + 2];
    float gx = 3.f * (tr - tl) + 10.f * (mr - ml) + 3.f * (br - bl);
    float gy = 3.f * (bl - tl) + 10.f * (bm - tm) + 3.f * (br - tr);
    return fabsf(gx) + fabsf(gy);
}

// Build r[0..9] (cols c0-1..c0+8) from a lane's two float4s + neighbor shfl.
// Wave spans the full 512-col row, so lane edges == image edges -> zero.
__device__ __forceinline__ void row_from_vec(float4 b0, float4 b1, int lane,
                                             float r[10]) {
    r[1] = b0.x; r[2] = b0.y; r[3] = b0.z; r[4] = b0.w;
    r[5] = b1.x; r[6] = b1.y; r[7] = b1.z; r[8] = b1.w;
    float lv = __shfl_up(b1.w, 1, 64);     // lane-1's col c0-1
    float rv = __shfl_down(b0.x, 1, 64);   // lane+1's col c0+8
    r[0] = (lane > 0)  ? lv : 0.f;
    r[9] = (lane < 63) ? rv : 0.f;
}

__device__ __forceinline__ void lds_row(const float* __restrict__ row, int lane,
                                        float r[10]) {
    float4 b0 = *reinterpret_cast<const float4*>(row + lane * 8);
    float4 b1 = *reinterpret_cast<const float4*>(row + lane * 8 + 4);
    row_from_vec(b0, b1, lane, r);
}

// Direct global row read (halo rows only); OOB row -> zeros. Wave-uniform h.
__device__ __forceinline__ void glb_row(const float* __restrict__ img, int h,
                                        int lane, float r[10]) {
    if ((unsigned)h < (unsigned)Hd) {
        const float* p = img + (size_t)h * Wd + lane * 8;
        float4 b0 = *reinterpret_cast<const float4*>(p);
        float4 b1 = *reinterpret_cast<const float4*>(p + 4);
        row_from_vec(b0, b1, lane, r);
    } else {
        #pragma unroll
        for (int k = 0; k < 10; ++k) r[k] = 0.f;
    }
}

__global__ void __launch_bounds__(256, 5)
scharr_loss_kernel(const float* __restrict__ x, const float* __restrict__ gt,
                   float* __restrict__ partials) {
    __shared__ float lb[2][RB][Wd];      // exactly 32 KB -> 5 blocks/CU

    int wid  = threadIdx.x >> 6;         // 0..3
    int lane = threadIdx.x & 63;

    // Bijective XCD swizzle (NBLK % 8 == 0): consecutive tiles of one image
    // land on the same XCD -> halo rows staged by the adjacent tile are L2 hits.
    int b    = blockIdx.x;
    int swz  = (b & 7) * (NBLK / 8) + (b >> 3);
    int img  = swz >> 6;                 // 64 tiles per image
    int h0   = (swz & 63) * RB;

    const float* __restrict__ xb = x  + (size_t)img * Hd * Wd;
    const float* __restrict__ gb = gt + (size_t)img * Hd * Wd;

    // --- stage: 32 chunks of 1 KB (2 img x 8 rows x 2 halves), 8 per wave.
    // All rows in-bounds: no OOB checks, no zero-fill writes.
    #pragma unroll
    for (int t = 0; t < 8; ++t) {
        int c    = wid + t * 4;          // 0..31, wave-uniform
        int im   = (c >= 16) ? 1 : 0;
        int cc   = c - im * 16;          // 0..15
        int row  = cc >> 1;              // 0..7
        int half = cc & 1;
        const float* __restrict__ sb = im ? gb : xb;
        gload_lds16(sb + (size_t)(h0 + row) * Wd + half * 256 + lane * 4,
                    &lb[im][row][half * 256]);
    }
    __syncthreads();                     // single vmcnt(0) drain per block

    // Fetch input row `grow` (global coords) for image im: LDS if staged here,
    // direct global (L2-hit via swizzle / zeros if OOB) for the 2 halo rows.
    auto get_row = [&](int im, int grow, float r[10]) {
        if (grow >= h0 && grow < h0 + RB) {
            lds_row(&lb[im][grow - h0][0], lane, r);
        } else {
            glb_row(im ? gb : xb, grow, lane, r);
        }
    };

    // --- compute: wave w owns output rows h0+2w, h0+2w+1 ---
    int orow = h0 + wid * 2;
    float rx[3][10], rg[3][10];
    get_row(0, orow - 1, rx[0]);
    get_row(0, orow,     rx[1]);
    get_row(1, orow - 1, rg[0]);
    get_row(1, orow,     rg[1]);

    float sum = 0.f;
    #pragma unroll
    for (int i = 0; i < 2; ++i) {
        const int c0 = i % 3, c1 = (i + 1) % 3, c2 = (i + 2) % 3;
        get_row(0, orow + i + 1, rx[c2]);
        get_row(1, orow + i + 1, rg[c2]);
        #pragma unroll
        for (int j = 0; j < 8; ++j) {
            float a = scharr_pix(rx[c0], rx[c1], rx[c2], j);
            float g = scharr_pix(rg[c0], rg[c1], rg[c2], j);
            sum += fabsf(a - g);
        }
    }

    // wave reduce; cross-wave partials reuse lb (keeps LDS at exactly 32 KB)
    #pragma unroll
    for (int off = 32; off > 0; off >>= 1)
        sum += __shfl_down(sum, off, 64);
    __syncthreads();                     // all waves done reading lb
    if (lane == 0) lb[0][0][wid] = sum;
    __syncthreads();
    if (threadIdx.x == 0)
        partials[blockIdx.x] = lb[0][0][0] + lb[0][0][1]
                             + lb[0][0][2] + lb[0][0][3];
}

__global__ void __launch_bounds__(256)
reduce_partials_kernel(const float* __restrict__ partials, float* __restrict__ out) {
    const float4* p4 = reinterpret_cast<const float4*>(partials);
    float s = 0.f;
    #pragma unroll
    for (int k = 0; k < NBLK / 4 / 256; ++k) {    // 3 float4s per thread
        float4 v = p4[k * 256 + threadIdx.x];
        s += v.x + v.y + v.z + v.w;
    }
    #pragma unroll
    for (int off = 32; off > 0; off >>= 1)
        s += __shfl_down(s, off, 64);
    __shared__ float ws[4];
    int lane = threadIdx.x & 63;
    int wid  = threadIdx.x >> 6;
    if (lane == 0) ws[wid] = s;
    __syncthreads();
    if (threadIdx.x == 0)
        out[0] = (ws[0] + ws[1] + ws[2] + ws[3]) * INV_N;
}

extern "C" void kernel_launch(void* const* d_in, const int* in_sizes, int n_in,
                              void* d_out, int out_size, void* d_ws, size_t ws_size,
                              hipStream_t stream) {
    const float* x  = (const float*)d_in[0];
    const float* gt = (const float*)d_in[1];
    float* out      = (float*)d_out;
    float* partials = (float*)d_ws;      // NBLK floats = 12 KB

    scharr_loss_kernel<<<NBLK, 256, 0, stream>>>(x, gt, partials);
    reduce_partials_kernel<<<1, 256, 0, stream>>>(partials, out);
}

// Round 12
// 25.875 us; speedup vs baseline: 1.2192x; 1.2192x over previous
//
#include <hip/hip_runtime.h>

#define Wd 512
#define Hd 512
#define NIMG 48                      // 16 batch * 3 channels
#define RB 16                       // output rows per tile
#define LR (RB + 2)                  // staged rows incl. vertical halo
#define NBLK (NIMG * (Hd / RB))      // 48*32 = 1536 blocks, one tile each
constexpr float INV_N = 1.0f / (float)((long long)NIMG * Hd * Wd);

// async global->LDS, 16 B per lane: HW writes lds_base + lane*16.
__device__ __forceinline__ void gload_lds16(const float* g, float* l) {
    __builtin_amdgcn_global_load_lds(
        (const __attribute__((address_space(1))) void*)g,
        (__attribute__((address_space(3))) void*)l, 16, 0, 0);
}

// Scharr on a 3x10 window; pixel j (0..7) uses cols j..j+2 of rows r0,r1,r2.
__device__ __forceinline__ float scharr_pix(const float r0[10], const float r1[10],
                                            const float r2[10], int j) {
    float tl = r0[j], tm = r0[j + 1], tr = r0[j + 2];
    float ml = r1[j],                  mr = r1[j + 2];
    float bl = r2[j], bm = r2[j + 1], br = r2[j + 2];
    float gx = 3.f * (tr - tl) + 10.f * (mr - ml) + 3.f * (br - bl);
    float gy = 3.f * (bl - tl) + 10.f * (bm - tm) + 3.f * (br - tr);
    return fabsf(gx) + fabsf(gy);
}

// Read cols [c0-1 .. c0+8] of one staged LDS row; halo via neighbor-lane shfl
// (wave spans the full 512-col row, lane edges == image edges -> zero).
__device__ __forceinline__ void lds_row(const float* __restrict__ row, int lane,
                                        float r[10]) {
    float4 b0 = *reinterpret_cast<const float4*>(row + lane * 8);
    float4 b1 = *reinterpret_cast<const float4*>(row + lane * 8 + 4);
    r[1] = b0.x; r[2] = b0.y; r[3] = b0.z; r[4] = b0.w;
    r[5] = b1.x; r[6] = b1.y; r[7] = b1.z; r[8] = b1.w;
    float lv = __shfl_up(b1.w, 1, 64);     // lane-1's col c0-1
    float rv = __shfl_down(b0.x, 1, 64);   // lane+1's col c0+8
    r[0] = (lane > 0)  ? lv : 0.f;
    r[9] = (lane < 63) ? rv : 0.f;
}

__global__ void __launch_bounds__(256)
scharr_loss_kernel(const float* __restrict__ x, const float* __restrict__ gt,
                   float* __restrict__ partials) {
    __shared__ float lb[2][LR][Wd];      // 72 KB -> 2 blocks/CU
    __shared__ float ws[4];

    int wid  = threadIdx.x >> 6;         // 0..3
    int lane = threadIdx.x & 63;

    // Bijective XCD swizzle (NBLK % 8 == 0): consecutive tiles of one image
    // land on the same XCD -> block-boundary halo rows are L2 hits.
    int b    = blockIdx.x;
    int swz  = (b & 7) * (NBLK / 8) + (b >> 3);
    int img  = swz >> 5;                 // 32 tiles per image
    int trow = swz & 31;
    int h0   = trow * RB;

    const float* __restrict__ xb = x  + (size_t)img * Hd * Wd;
    const float* __restrict__ gb = gt + (size_t)img * Hd * Wd;

    // --- stage img-x first (36 chunks of 1 KB, 9 per wave), then img-gt ---
    #pragma unroll
    for (int t = 0; t < 9; ++t) {
        int c    = wid + t * 4;          // 0..35, wave-uniform
        int row  = c >> 1;
        int half = c & 1;
        int gh   = h0 - 1 + row;
        float* dst = &lb[0][row][half * 256];
        if ((unsigned)gh < (unsigned)Hd) {
            gload_lds16(xb + (size_t)gh * Wd + half * 256 + lane * 4, dst);
        } else {
            *reinterpret_cast<float4*>(dst + lane * 4) =
                make_float4(0.f, 0.f, 0.f, 0.f);
        }
    }
    #pragma unroll
    for (int t = 0; t < 9; ++t) {
        int c    = wid + t * 4;
        int row  = c >> 1;
        int half = c & 1;
        int gh   = h0 - 1 + row;
        float* dst = &lb[1][row][half * 256];
        if ((unsigned)gh < (unsigned)Hd) {
            gload_lds16(gb + (size_t)gh * Wd + half * 256 + lane * 4, dst);
        } else {
            *reinterpret_cast<float4*>(dst + lane * 4) =
                make_float4(0.f, 0.f, 0.f, 0.f);
        }
    }

    // Counted wait: own img-x loads complete (in-order vmcnt retirement; each
    // wave has 9 img-gt issues in flight, 8 on edge tiles -> vmcnt(8) covers
    // both, over-waiting by at most one chunk). img-gt keeps streaming.
    asm volatile("s_waitcnt vmcnt(8) lgkmcnt(0)" ::: "memory");
    __builtin_amdgcn_sched_barrier(0);
    __builtin_amdgcn_s_barrier();
    __builtin_amdgcn_sched_barrier(0);

    // --- phase X: scharr(x) for wave's 4 rows x 8 cols into registers,
    //     overlapped with img-gt's in-flight loads ---
    int lr = wid * 4;                    // lb row base for this wave's window
    float gx[4][8];
    {
        float r[3][10];
        lds_row(&lb[0][lr][0],     lane, r[0]);
        lds_row(&lb[0][lr + 1][0], lane, r[1]);
        #pragma unroll
        for (int i = 0; i < 4; ++i) {
            const int c0 = i % 3, c1 = (i + 1) % 3, c2 = (i + 2) % 3;
            lds_row(&lb[0][lr + i + 2][0], lane, r[c2]);
            #pragma unroll
            for (int j = 0; j < 8; ++j)
                gx[i][j] = scharr_pix(r[c0], r[c1], r[c2], j);
        }
    }

    __syncthreads();                     // img-gt loads landed (mostly drained)

    // --- phase G: scharr(gt), accumulate |gx - gg| ---
    float sum = 0.f;
    {
        float r[3][10];
        lds_row(&lb[1][lr][0],     lane, r[0]);
        lds_row(&lb[1][lr + 1][0], lane, r[1]);
        #pragma unroll
        for (int i = 0; i < 4; ++i) {
            const int c0 = i % 3, c1 = (i + 1) % 3, c2 = (i + 2) % 3;
            lds_row(&lb[1][lr + i + 2][0], lane, r[c2]);
            #pragma unroll
            for (int j = 0; j < 8; ++j) {
                float gg = scharr_pix(r[c0], r[c1], r[c2], j);
                sum += fabsf(gx[i][j] - gg);
            }
        }
    }

    // wave reduce -> cross-wave LDS -> one plain store per block
    #pragma unroll
    for (int off = 32; off > 0; off >>= 1)
        sum += __shfl_down(sum, off, 64);
    if (lane == 0) ws[wid] = sum;
    __syncthreads();
    if (threadIdx.x == 0)
        partials[blockIdx.x] = ws[0] + ws[1] + ws[2] + ws[3];
}

__global__ void __launch_bounds__(256)
reduce_partials_kernel(const float* __restrict__ partials, float* __restrict__ out) {
    float s = 0.f;
    #pragma unroll
    for (int k = 0; k < NBLK / 256; ++k)          // 6 iterations
        s += partials[k * 256 + threadIdx.x];
    #pragma unroll
    for (int off = 32; off > 0; off >>= 1)
        s += __shfl_down(s, off, 64);
    __shared__ float ws[4];
    int lane = threadIdx.x & 63;
    int wid  = threadIdx.x >> 6;
    if (lane == 0) ws[wid] = s;
    __syncthreads();
    if (threadIdx.x == 0)
        out[0] = (ws[0] + ws[1] + ws[2] + ws[3]) * INV_N;
}

extern "C" void kernel_launch(void* const* d_in, const int* in_sizes, int n_in,
                              void* d_out, int out_size, void* d_ws, size_t ws_size,
                              hipStream_t stream) {
    const float* x  = (const float*)d_in[0];
    const float* gt = (const float*)d_in[1];
    float* out      = (float*)d_out;
    float* partials = (float*)d_ws;      // NBLK floats = 6 KB

    scharr_loss_kernel<<<NBLK, 256, 0, stream>>>(x, gt, partials);
    reduce_partials_kernel<<<1, 256, 0, stream>>>(partials, out);
}